// Round 1
// baseline (651.103 us; speedup 1.0000x reference)
//
#include <hip/hip_runtime.h>

typedef float f32x4 __attribute__((ext_vector_type(4)));
typedef short s16x8 __attribute__((ext_vector_type(8)));

#define MFMA16(A,B,C) __builtin_amdgcn_mfma_f32_16x16x32_bf16((A),(B),(C),0,0,0)

__device__ __forceinline__ short f2bf(float f) {
  union { float f; unsigned u; } v; v.f = f;
  unsigned r = v.u + 0x7FFFu + ((v.u >> 16) & 1u);   // RNE
  return (short)(r >> 16);
}

// ---------------- prep: transpose weights to bf16[N][K], gather bias table ----
__global__ __launch_bounds__(256) void prep_kernel(
    const float* __restrict__ Wqkv, const float* __restrict__ Wo,
    const float* __restrict__ posb, const int* __restrict__ relp,
    short* __restrict__ WqkvT, short* __restrict__ WoT, float* __restrict__ biasF)
{
  int i = blockIdx.x * 256 + threadIdx.x;
  if (i < 1152 * 384) {
    int n = i / 384, k = i % 384;
    WqkvT[i] = f2bf(Wqkv[k * 1152 + n]);
  } else if (i < 1152 * 384 + 384 * 384) {
    int j = i - 1152 * 384;
    int n = j / 384, k = j % 384;
    WoT[j] = f2bf(Wo[k * 384 + n]);
  } else {
    int j = i - (1152 * 384 + 384 * 384);    // j < 12*64*64 = 49152
    int h = j >> 12, qk = j & 4095;
    biasF[j] = posb[h * 16129 + relp[qk]];
  }
}

// ---------------- fused per-window QKV + attention ----------------------------
// grid = 1568 (= 32*49) blocks, 256 threads (4 waves). Wave w handles heads
// {w, w+4, w+8}. Per head: 64x96x384 QKV GEMM (MFMA 16x16x32 bf16), LDS
// round-trip for operand transposes, swapped QK^T (S^T = K·Q^T) so softmax is
// per-lane + shfl_xor(16/32), P^T repacked to B-fragments in-register.
__global__ __launch_bounds__(256) void attn_fused(
    const float* __restrict__ X, const short* __restrict__ WqkvT,
    const float* __restrict__ biasF, short* __restrict__ AO)
{
  __shared__ short lds[29696];          // 4 waves * (Q[64][40] + K[64][40] + Vt[32][72])
  const int bw = blockIdx.x;
  const int wv = threadIdx.x >> 6;
  const int l  = threadIdx.x & 63;
  const int lr = l & 15, lg = l >> 4;

  short* Qs  = lds + wv * 7424;
  short* Ks  = Qs + 2560;
  short* Vts = Ks + 2560;

  const float* Xt = X + (size_t)bw * 64 * 384;

  for (int hh = 0; hh < 3; ++hh) {
    const int h = wv + hh * 4;

    // ---- QKV projection for this head: 64 x (3*32), K = 384 ----
    f32x4 acc[4][6];
#pragma unroll
    for (int fm = 0; fm < 4; ++fm)
#pragma unroll
      for (int fn = 0; fn < 6; ++fn) acc[fm][fn] = (f32x4)0.0f;

    for (int ks = 0; ks < 12; ++ks) {
      s16x8 a[4];
#pragma unroll
      for (int fm = 0; fm < 4; ++fm) {
        const float* p = Xt + (fm * 16 + lr) * 384 + ks * 32 + lg * 8;
        float4 x0 = *(const float4*)p;
        float4 x1 = *(const float4*)(p + 4);
        s16x8 t;
        t[0] = f2bf(x0.x); t[1] = f2bf(x0.y); t[2] = f2bf(x0.z); t[3] = f2bf(x0.w);
        t[4] = f2bf(x1.x); t[5] = f2bf(x1.y); t[6] = f2bf(x1.z); t[7] = f2bf(x1.w);
        a[fm] = t;
      }
#pragma unroll
      for (int fn = 0; fn < 6; ++fn) {
        const int nb = (fn >> 1) * 384 + h * 32 + (fn & 1) * 16 + lr;
        s16x8 b = *(const s16x8*)(WqkvT + (size_t)nb * 384 + ks * 32 + lg * 8);
#pragma unroll
        for (int fm = 0; fm < 4; ++fm)
          acc[fm][fn] = MFMA16(a[fm], b, acc[fm][fn]);
      }
    }

    // ---- scatter Q, K, V^T to wave-private LDS ----
#pragma unroll
    for (int fm = 0; fm < 4; ++fm) {
#pragma unroll
      for (int fn = 0; fn < 6; ++fn) {
        const int sel = fn >> 1;
        const int d = (fn & 1) * 16 + lr;            // C/D col = lane&15
        if (sel < 2) {
          short* dst = (sel ? Ks : Qs) + (fm * 16 + lg * 4) * 40 + d;
#pragma unroll
          for (int r = 0; r < 4; ++r) dst[r * 40] = f2bf(acc[fm][fn][r]);
        } else {                                      // V stored transposed [d][s]
          short4 v;
          v.x = f2bf(acc[fm][fn][0]); v.y = f2bf(acc[fm][fn][1]);
          v.z = f2bf(acc[fm][fn][2]); v.w = f2bf(acc[fm][fn][3]);
          *(short4*)(Vts + d * 72 + fm * 16 + lg * 4) = v;
        }
      }
    }

    // ---- S^T = K · Q^T : frags (fk rows=kt, fq cols=q), K-dim = 32 ----
    s16x8 ka[4], qb[4];
#pragma unroll
    for (int f = 0; f < 4; ++f) {
      ka[f] = *(const s16x8*)(Ks + (f * 16 + lr) * 40 + lg * 8);
      qb[f] = *(const s16x8*)(Qs + (f * 16 + lr) * 40 + lg * 8);
    }
    f32x4 st[4][4];
#pragma unroll
    for (int fk = 0; fk < 4; ++fk)
#pragma unroll
      for (int fq = 0; fq < 4; ++fq)
        st[fk][fq] = MFMA16(ka[fk], qb[fq], (f32x4)0.0f);

    // ---- scale + bias + softmax over kt (per q column) ----
    const float* bh = biasF + h * 4096;
#pragma unroll
    for (int fq = 0; fq < 4; ++fq) {
      const int q = fq * 16 + lr;
      float mx = -3.0e38f;
#pragma unroll
      for (int fk = 0; fk < 4; ++fk)
#pragma unroll
        for (int r = 0; r < 4; ++r) {
          const int kt = fk * 16 + lg * 4 + r;       // C/D row id
          float v = st[fk][fq][r] * 0.17677669529663687f + bh[q * 64 + kt];
          st[fk][fq][r] = v;
          mx = fmaxf(mx, v);
        }
      mx = fmaxf(mx, __shfl_xor(mx, 16));
      mx = fmaxf(mx, __shfl_xor(mx, 32));
      float sm = 0.0f;
#pragma unroll
      for (int fk = 0; fk < 4; ++fk)
#pragma unroll
        for (int r = 0; r < 4; ++r) {
          float e = __expf(st[fk][fq][r] - mx);
          st[fk][fq][r] = e;
          sm += e;
        }
      sm += __shfl_xor(sm, 16);
      sm += __shfl_xor(sm, 32);
      const float inv = 1.0f / sm;
#pragma unroll
      for (int fk = 0; fk < 4; ++fk)
#pragma unroll
        for (int r = 0; r < 4; ++r) st[fk][fq][r] *= inv;
    }

    // ---- O^T = V^T · P^T : rows d, cols q; K-dim = 64 (2 blocks of 32) ----
    // sigma(g,j) = 32*kb + 16*(j>>2) + 4*g + (j&3) on BOTH operands.
    s16x8 va[2][2];
#pragma unroll
    for (int fd = 0; fd < 2; ++fd)
#pragma unroll
      for (int kb = 0; kb < 2; ++kb) {
        short4 v0 = *(const short4*)(Vts + (fd * 16 + lr) * 72 + kb * 32 + lg * 4);
        short4 v1 = *(const short4*)(Vts + (fd * 16 + lr) * 72 + kb * 32 + 16 + lg * 4);
        s16x8 t;
        t[0] = v0.x; t[1] = v0.y; t[2] = v0.z; t[3] = v0.w;
        t[4] = v1.x; t[5] = v1.y; t[6] = v1.z; t[7] = v1.w;
        va[fd][kb] = t;
      }
    f32x4 ot[2][4];
#pragma unroll
    for (int fd = 0; fd < 2; ++fd)
#pragma unroll
      for (int fq = 0; fq < 4; ++fq) ot[fd][fq] = (f32x4)0.0f;
#pragma unroll
    for (int kb = 0; kb < 2; ++kb)
#pragma unroll
      for (int fq = 0; fq < 4; ++fq) {
        s16x8 pb;
#pragma unroll
        for (int j = 0; j < 8; ++j)
          pb[j] = f2bf(st[2 * kb + (j >> 2)][fq][j & 3]);   // lane-local repack
#pragma unroll
        for (int fd = 0; fd < 2; ++fd)
          ot[fd][fq] = MFMA16(va[fd][kb], pb, ot[fd][fq]);
      }

    // ---- O epilogue: stage [q][d] in LDS (reuse Qs), write coalesced rows ----
#pragma unroll
    for (int fd = 0; fd < 2; ++fd)
#pragma unroll
      for (int fq = 0; fq < 4; ++fq)
#pragma unroll
        for (int r = 0; r < 4; ++r)
          Qs[(fq * 16 + lr) * 40 + fd * 16 + lg * 4 + r] = f2bf(ot[fd][fq][r]);
    short* dst = AO + ((size_t)bw * 64 + l) * 384 + h * 32;
    int4 o0 = *(const int4*)(Qs + l * 40);
    int4 o1 = *(const int4*)(Qs + l * 40 + 8);
    int4 o2 = *(const int4*)(Qs + l * 40 + 16);
    int4 o3 = *(const int4*)(Qs + l * 40 + 24);
    *(int4*)(dst)      = o0;
    *(int4*)(dst + 8)  = o1;
    *(int4*)(dst + 16) = o2;
    *(int4*)(dst + 24) = o3;
  }
}

// ---------------- output projection: out = AO(bf16) @ Wo + bo, f32 out --------
// M=100352 (784 tiles), N=384 (3 tiles), K=384 (6 steps of 64). 128x128 tile,
// 4 waves in 2x2, reg-staged LDS, single-buffered.
__global__ __launch_bounds__(256) void proj_kernel(
    const short* __restrict__ AO, const short* __restrict__ WoT,
    const float* __restrict__ bo, float* __restrict__ out)
{
  __shared__ short Al[128 * 64];
  __shared__ short Bl[128 * 64];
  const int bid = blockIdx.x;
  const int nt = bid % 3, mt = bid / 3;
  const int t = threadIdx.x;
  const int wv = t >> 6, l = t & 63, lr = l & 15, lg = l >> 4;
  const int wm = wv >> 1, wn = wv & 1;

  f32x4 acc[4][4];
#pragma unroll
  for (int fm = 0; fm < 4; ++fm)
#pragma unroll
    for (int fn = 0; fn < 4; ++fn) acc[fm][fn] = (f32x4)0.0f;

  for (int ks = 0; ks < 6; ++ks) {
    int4 av[4], bv[4];
#pragma unroll
    for (int c = 0; c < 4; ++c) {
      const int chunk = c * 256 + t;
      const int row = chunk >> 3, cc = chunk & 7;
      av[c] = *(const int4*)(AO  + (size_t)(mt * 128 + row) * 384 + ks * 64 + cc * 8);
      bv[c] = *(const int4*)(WoT + (size_t)(nt * 128 + row) * 384 + ks * 64 + cc * 8);
    }
    __syncthreads();
#pragma unroll
    for (int c = 0; c < 4; ++c) {
      const int chunk = c * 256 + t;
      const int row = chunk >> 3, cc = chunk & 7;
      *(int4*)(Al + row * 64 + cc * 8) = av[c];
      *(int4*)(Bl + row * 64 + cc * 8) = bv[c];
    }
    __syncthreads();
#pragma unroll
    for (int kk = 0; kk < 2; ++kk) {
      s16x8 af[4], bf[4];
#pragma unroll
      for (int f = 0; f < 4; ++f) {
        af[f] = *(const s16x8*)(Al + (wm * 64 + f * 16 + lr) * 64 + kk * 32 + lg * 8);
        bf[f] = *(const s16x8*)(Bl + (wn * 64 + f * 16 + lr) * 64 + kk * 32 + lg * 8);
      }
#pragma unroll
      for (int fm = 0; fm < 4; ++fm)
#pragma unroll
        for (int fn = 0; fn < 4; ++fn)
          acc[fm][fn] = MFMA16(af[fm], bf[fn], acc[fm][fn]);
    }
  }

#pragma unroll
  for (int fn = 0; fn < 4; ++fn) {
    const int n = nt * 128 + wn * 64 + fn * 16 + lr;
    const float bias = bo[n];
#pragma unroll
    for (int fm = 0; fm < 4; ++fm) {
      const int m0 = mt * 128 + wm * 64 + fm * 16 + lg * 4;
#pragma unroll
      for (int r = 0; r < 4; ++r)
        out[(size_t)(m0 + r) * 384 + n] = acc[fm][fn][r] + bias;
    }
  }
}

extern "C" void kernel_launch(void* const* d_in, const int* in_sizes, int n_in,
                              void* d_out, int out_size, void* d_ws, size_t ws_size,
                              hipStream_t stream)
{
  const float* X    = (const float*)d_in[0];
  const float* Wqkv = (const float*)d_in[1];
  const float* posb = (const float*)d_in[2];
  const float* Wo   = (const float*)d_in[3];
  const float* bo   = (const float*)d_in[4];
  const int*   relp = (const int*)d_in[5];
  float* out = (float*)d_out;

  // workspace carve (78,446,592 bytes total)
  char* ws = (char*)d_ws;
  short* WqkvT = (short*)(ws);                 //   884,736 B : bf16 [1152][384]
  short* WoT   = (short*)(ws + 884736);        //   294,912 B : bf16 [384][384]
  float* biasF = (float*)(ws + 1179648);       //   196,608 B : f32  [12][64][64]
  short* AO    = (short*)(ws + 1376256);       // 77,070,336 B : bf16 [100352][384]

  prep_kernel<<<2496, 256, 0, stream>>>(Wqkv, Wo, posb, relp, WqkvT, WoT, biasF);
  attn_fused<<<1568, 256, 0, stream>>>(X, WqkvT, biasF, AO);
  proj_kernel<<<2352, 256, 0, stream>>>(AO, WoT, bo, out);
}

// Round 2
// 571.406 us; speedup vs baseline: 1.1395x; 1.1395x over previous
//
#include <hip/hip_runtime.h>

typedef float f32x4 __attribute__((ext_vector_type(4)));
typedef short s16x8 __attribute__((ext_vector_type(8)));

#define MFMA16(A,B,C) __builtin_amdgcn_mfma_f32_16x16x32_bf16((A),(B),(C),0,0,0)

__device__ __forceinline__ short f2bf(float f) {
  union { float f; unsigned u; } v; v.f = f;
  unsigned r = v.u + 0x7FFFu + ((v.u >> 16) & 1u);   // RNE
  return (short)(r >> 16);
}

__device__ __forceinline__ void gload_lds16(const void* g, void* l) {
  __builtin_amdgcn_global_load_lds(
      (const __attribute__((address_space(1))) unsigned*)g,
      (__attribute__((address_space(3))) unsigned*)l, 16, 0, 0);
}

// ---------------- prep: transpose weights to bf16[N][K], gather bias table ----
__global__ __launch_bounds__(256) void prep_kernel(
    const float* __restrict__ Wqkv, const float* __restrict__ Wo,
    const float* __restrict__ posb, const int* __restrict__ relp,
    short* __restrict__ WqkvT, short* __restrict__ WoT, float* __restrict__ biasF)
{
  int i = blockIdx.x * 256 + threadIdx.x;
  if (i < 1152 * 384) {
    int n = i / 384, k = i % 384;
    WqkvT[i] = f2bf(Wqkv[k * 1152 + n]);
  } else if (i < 1152 * 384 + 384 * 384) {
    int j = i - 1152 * 384;
    int n = j / 384, k = j % 384;
    WoT[j] = f2bf(Wo[k * 384 + n]);
  } else {
    int j = i - (1152 * 384 + 384 * 384);    // j < 12*64*64 = 49152
    int h = j >> 12, qk = j & 4095;
    biasF[j] = posb[h * 16129 + relp[qk]];
  }
}

// ---------------- QKV GEMM: C = X(100352x384,f32) @ WqkvT^T -> Q/K/Vt bf16 ----
// 128x128 tile, 4 waves 2x2, BK=64 (6 k-steps). A: reg-staged f32->bf16 into
// padded [128][72] LDS (conflict-free). B: global_load_lds into linear
// [128][64] LDS with XOR-chunk swizzle on BOTH source and read (rule #21).
// Epilogue: nt<6 -> Q/K rows [win][h][tok][32] via LDS re-stage; nt>=6 -> Vt
// [win][h][d][tok] direct transposed short4 stores.
__global__ __launch_bounds__(256) void qkv_gemm(
    const float* __restrict__ X, const short* __restrict__ WqkvT,
    short* __restrict__ Qb, short* __restrict__ Kb, short* __restrict__ Vtb)
{
  __shared__ short lds[17408];           // Al[128*72] + Bl[128*64] = 34816 B
  short* Al = lds;                       // 9216 shorts
  short* Bl = lds + 9216;                // 8192 shorts

  const int bid = blockIdx.x;
  const int wg = (bid & 7) * 882 + (bid >> 3);   // XCD swizzle (7056 = 8*882)
  const int nt = wg % 9, mt = wg / 9;
  const int t = threadIdx.x;
  const int wv = t >> 6, l = t & 63, lr = l & 15, lg = l >> 4;
  const int wm = wv >> 1, wn = wv & 1;

  f32x4 acc[4][4];
#pragma unroll
  for (int fm = 0; fm < 4; ++fm)
#pragma unroll
    for (int fn = 0; fn < 4; ++fn) acc[fm][fn] = (f32x4)0.0f;

  const int ra = t >> 1, ca = (t & 1) * 32;
  const float* Ag = X + (size_t)(mt * 128 + ra) * 384 + ca;

  for (int ks = 0; ks < 6; ++ks) {
    // A: global f32 loads into regs (overlaps previous MFMAs)
    float4 xa[8];
#pragma unroll
    for (int j = 0; j < 8; ++j) xa[j] = *(const float4*)(Ag + ks * 64 + j * 4);

    __syncthreads();     // previous tile's compute done; LDS free

    // B: 4x global_load_lds per thread, linear LDS dest, XOR-swizzled source
#pragma unroll
    for (int c = 0; c < 4; ++c) {
      const int row = (c * 4 + wv) * 8 + (l >> 3);
      const int cg = (l & 7) ^ (row & 7);          // source chunk (involution)
      gload_lds16(WqkvT + (size_t)(nt * 128 + row) * 384 + ks * 64 + cg * 8,
                  Bl + row * 64 + (l & 7) * 8);
    }
    // A: convert + ds_write to padded rows
#pragma unroll
    for (int jj = 0; jj < 4; ++jj) {
      s16x8 p;
      p[0] = f2bf(xa[2*jj].x);   p[1] = f2bf(xa[2*jj].y);
      p[2] = f2bf(xa[2*jj].z);   p[3] = f2bf(xa[2*jj].w);
      p[4] = f2bf(xa[2*jj+1].x); p[5] = f2bf(xa[2*jj+1].y);
      p[6] = f2bf(xa[2*jj+1].z); p[7] = f2bf(xa[2*jj+1].w);
      *(s16x8*)(Al + ra * 72 + ca + jj * 8) = p;
    }
    __syncthreads();     // drains vmcnt (gll) + lgkmcnt (ds_write)

#pragma unroll
    for (int kk = 0; kk < 2; ++kk) {
      s16x8 af[4], bf[4];
#pragma unroll
      for (int f = 0; f < 4; ++f) {
        const int arow = wm * 64 + f * 16 + lr;
        af[f] = *(const s16x8*)(Al + arow * 72 + kk * 32 + lg * 8);
        const int brow = wn * 64 + f * 16 + lr;
        const int cs = (kk * 4 + lg) ^ (brow & 7);  // same involution on read
        bf[f] = *(const s16x8*)(Bl + brow * 64 + cs * 8);
      }
#pragma unroll
      for (int fm = 0; fm < 4; ++fm)
#pragma unroll
        for (int fn = 0; fn < 4; ++fn)
          acc[fm][fn] = MFMA16(af[fm], bf[fn], acc[fm][fn]);
    }
  }

  // ---- epilogue ----
  const int sel = nt / 3, hq = (nt % 3) * 4;
  if (sel == 2) {
    // V: direct transposed stores Vt[win][h][d][tok]
#pragma unroll
    for (int fm = 0; fm < 4; ++fm)
#pragma unroll
      for (int fn = 0; fn < 4; ++fn) {
        const int m0 = wm * 64 + fm * 16 + lg * 4;
        const int win = m0 >> 6, tok0 = m0 & 63;
        const int n = wn * 64 + fn * 16 + lr;
        const int hl = n >> 5, d = n & 31;
        short4 v;
        v.x = f2bf(acc[fm][fn][0]); v.y = f2bf(acc[fm][fn][1]);
        v.z = f2bf(acc[fm][fn][2]); v.w = f2bf(acc[fm][fn][3]);
        *(short4*)(Vtb + (size_t)(mt * 2 + win) * 24576 + (hq + hl) * 2048
                   + d * 64 + tok0) = v;
      }
  } else {
    // Q/K: re-stage tile in LDS [128][136], then coalesced 64B row writes
    __syncthreads();
    short* Cl = lds;     // 128*136 = 17408 shorts, exactly fits
#pragma unroll
    for (int fm = 0; fm < 4; ++fm)
#pragma unroll
      for (int fn = 0; fn < 4; ++fn)
#pragma unroll
        for (int r = 0; r < 4; ++r)
          Cl[(wm * 64 + fm * 16 + lg * 4 + r) * 136 + wn * 64 + fn * 16 + lr] =
              f2bf(acc[fm][fn][r]);
    __syncthreads();
    short* dst0 = (sel ? Kb : Qb) + (size_t)mt * 2 * 24576;
#pragma unroll
    for (int rr = 0; rr < 2; ++rr) {
      const int ro = t * 2 + rr;
      const int win = ro >> 8, hl = (ro >> 6) & 3, tok = ro & 63;
      const int m = win * 64 + tok;
      const short* srcl = Cl + m * 136 + hl * 32;
      int4 a0 = *(const int4*)(srcl);
      int4 a1 = *(const int4*)(srcl + 8);
      int4 a2 = *(const int4*)(srcl + 16);
      int4 a3 = *(const int4*)(srcl + 24);
      short* dp = dst0 + win * 24576 + (hq + hl) * 2048 + tok * 32;
      *(int4*)(dp)      = a0;
      *(int4*)(dp + 8)  = a1;
      *(int4*)(dp + 16) = a2;
      *(int4*)(dp + 24) = a3;
    }
  }
}

// ---------------- attention: one wave per (window, head) ----------------------
__global__ __launch_bounds__(256) void attn_split(
    const short* __restrict__ Qb, const short* __restrict__ Kb,
    const short* __restrict__ Vtb, const float* __restrict__ biasF,
    short* __restrict__ AO)
{
  __shared__ short obuf[10240];          // 4 waves * [64][40]
  const int bid = blockIdx.x;
  const int wg = (bid & 7) * 588 + (bid >> 3);   // XCD swizzle (4704 = 8*588)
  const int wv = threadIdx.x >> 6;
  const int l = threadIdx.x & 63, lr = l & 15, lg = l >> 4;
  const int p = wg * 4 + wv;                     // (w,h) pair, p = w*12 + h
  const int w = p / 12, h = p % 12;

  const short* Kp = Kb + (size_t)p * 2048;
  const short* Qp = Qb + (size_t)p * 2048;
  const short* Vp = Vtb + (size_t)p * 2048;
  const float* bh = biasF + h * 4096;

  // fragment loads straight from global (already in MFMA layout)
  s16x8 ka[4], qf[4];
#pragma unroll
  for (int f = 0; f < 4; ++f) {
    ka[f] = *(const s16x8*)(Kp + (f * 16 + lr) * 32 + lg * 8);
    qf[f] = *(const s16x8*)(Qp + (f * 16 + lr) * 32 + lg * 8);
  }
  s16x8 va[2][2];
#pragma unroll
  for (int fd = 0; fd < 2; ++fd)
#pragma unroll
    for (int kb = 0; kb < 2; ++kb) {
      short4 v0 = *(const short4*)(Vp + (fd * 16 + lr) * 64 + kb * 32 + lg * 4);
      short4 v1 = *(const short4*)(Vp + (fd * 16 + lr) * 64 + kb * 32 + 16 + lg * 4);
      s16x8 tv;
      tv[0] = v0.x; tv[1] = v0.y; tv[2] = v0.z; tv[3] = v0.w;
      tv[4] = v1.x; tv[5] = v1.y; tv[6] = v1.z; tv[7] = v1.w;
      va[fd][kb] = tv;
    }

  // S^T = K·Q^T  (rows kt, cols q), K-dim 32
  f32x4 st[4][4];
#pragma unroll
  for (int fk = 0; fk < 4; ++fk)
#pragma unroll
    for (int fq = 0; fq < 4; ++fq)
      st[fk][fq] = MFMA16(ka[fk], qf[fq], (f32x4)0.0f);

  // scale + bias + softmax over kt (per q column, per-lane + shfl 16/32)
#pragma unroll
  for (int fq = 0; fq < 4; ++fq) {
    const int q = fq * 16 + lr;
    float4 bv[4];
#pragma unroll
    for (int fk = 0; fk < 4; ++fk)
      bv[fk] = *(const float4*)(bh + q * 64 + fk * 16 + lg * 4);
    float mx = -3.0e38f;
#pragma unroll
    for (int fk = 0; fk < 4; ++fk)
#pragma unroll
      for (int r = 0; r < 4; ++r) {
        float v = st[fk][fq][r] * 0.17677669529663687f + ((const float*)&bv[fk])[r];
        st[fk][fq][r] = v;
        mx = fmaxf(mx, v);
      }
    mx = fmaxf(mx, __shfl_xor(mx, 16));
    mx = fmaxf(mx, __shfl_xor(mx, 32));
    float sm = 0.0f;
#pragma unroll
    for (int fk = 0; fk < 4; ++fk)
#pragma unroll
      for (int r = 0; r < 4; ++r) {
        float e = __expf(st[fk][fq][r] - mx);
        st[fk][fq][r] = e;
        sm += e;
      }
    sm += __shfl_xor(sm, 16);
    sm += __shfl_xor(sm, 32);
    const float inv = 1.0f / sm;
#pragma unroll
    for (int fk = 0; fk < 4; ++fk)
#pragma unroll
      for (int r = 0; r < 4; ++r) st[fk][fq][r] *= inv;
  }

  // O^T = V^T · P^T ; sigma(g,j)=32kb+16(j>>2)+4g+(j&3) on both operands
  f32x4 ot[2][4];
#pragma unroll
  for (int fd = 0; fd < 2; ++fd)
#pragma unroll
    for (int fq = 0; fq < 4; ++fq) ot[fd][fq] = (f32x4)0.0f;
#pragma unroll
  for (int kb = 0; kb < 2; ++kb)
#pragma unroll
    for (int fq = 0; fq < 4; ++fq) {
      s16x8 pb;
#pragma unroll
      for (int j = 0; j < 8; ++j)
        pb[j] = f2bf(st[2 * kb + (j >> 2)][fq][j & 3]);   // lane-local repack
#pragma unroll
      for (int fd = 0; fd < 2; ++fd)
        ot[fd][fq] = MFMA16(va[fd][kb], pb, ot[fd][fq]);
    }

  // epilogue: stage [q][d] per-wave in LDS, write coalesced 16B rows
  short* ob = obuf + wv * 2560;
#pragma unroll
  for (int fd = 0; fd < 2; ++fd)
#pragma unroll
    for (int fq = 0; fq < 4; ++fq)
#pragma unroll
      for (int r = 0; r < 4; ++r)
        ob[(fq * 16 + lr) * 40 + fd * 16 + lg * 4 + r] = f2bf(ot[fd][fq][r]);
  short* dst = AO + ((size_t)w * 64 + l) * 384 + h * 32;
  int4 o0 = *(const int4*)(ob + l * 40);
  int4 o1 = *(const int4*)(ob + l * 40 + 8);
  int4 o2 = *(const int4*)(ob + l * 40 + 16);
  int4 o3 = *(const int4*)(ob + l * 40 + 24);
  *(int4*)(dst)      = o0;
  *(int4*)(dst + 8)  = o1;
  *(int4*)(dst + 16) = o2;
  *(int4*)(dst + 24) = o3;
}

// ---------------- round-1 fused path (fallback if ws too small) ---------------
__global__ __launch_bounds__(256) void attn_fused(
    const float* __restrict__ X, const short* __restrict__ WqkvT,
    const float* __restrict__ biasF, short* __restrict__ AO)
{
  __shared__ short lds[29696];
  const int bw = blockIdx.x;
  const int wv = threadIdx.x >> 6;
  const int l  = threadIdx.x & 63;
  const int lr = l & 15, lg = l >> 4;

  short* Qs  = lds + wv * 7424;
  short* Ks  = Qs + 2560;
  short* Vts = Ks + 2560;

  const float* Xt = X + (size_t)bw * 64 * 384;

  for (int hh = 0; hh < 3; ++hh) {
    const int h = wv + hh * 4;
    f32x4 acc[4][6];
#pragma unroll
    for (int fm = 0; fm < 4; ++fm)
#pragma unroll
      for (int fn = 0; fn < 6; ++fn) acc[fm][fn] = (f32x4)0.0f;

    for (int ks = 0; ks < 12; ++ks) {
      s16x8 a[4];
#pragma unroll
      for (int fm = 0; fm < 4; ++fm) {
        const float* p = Xt + (fm * 16 + lr) * 384 + ks * 32 + lg * 8;
        float4 x0 = *(const float4*)p;
        float4 x1 = *(const float4*)(p + 4);
        s16x8 tt;
        tt[0] = f2bf(x0.x); tt[1] = f2bf(x0.y); tt[2] = f2bf(x0.z); tt[3] = f2bf(x0.w);
        tt[4] = f2bf(x1.x); tt[5] = f2bf(x1.y); tt[6] = f2bf(x1.z); tt[7] = f2bf(x1.w);
        a[fm] = tt;
      }
#pragma unroll
      for (int fn = 0; fn < 6; ++fn) {
        const int nb = (fn >> 1) * 384 + h * 32 + (fn & 1) * 16 + lr;
        s16x8 b = *(const s16x8*)(WqkvT + (size_t)nb * 384 + ks * 32 + lg * 8);
#pragma unroll
        for (int fm = 0; fm < 4; ++fm)
          acc[fm][fn] = MFMA16(a[fm], b, acc[fm][fn]);
      }
    }

#pragma unroll
    for (int fm = 0; fm < 4; ++fm) {
#pragma unroll
      for (int fn = 0; fn < 6; ++fn) {
        const int sel = fn >> 1;
        const int d = (fn & 1) * 16 + lr;
        if (sel < 2) {
          short* dst = (sel ? Ks : Qs) + (fm * 16 + lg * 4) * 40 + d;
#pragma unroll
          for (int r = 0; r < 4; ++r) dst[r * 40] = f2bf(acc[fm][fn][r]);
        } else {
          short4 v;
          v.x = f2bf(acc[fm][fn][0]); v.y = f2bf(acc[fm][fn][1]);
          v.z = f2bf(acc[fm][fn][2]); v.w = f2bf(acc[fm][fn][3]);
          *(short4*)(Vts + d * 72 + fm * 16 + lg * 4) = v;
        }
      }
    }

    s16x8 ka[4], qb[4];
#pragma unroll
    for (int f = 0; f < 4; ++f) {
      ka[f] = *(const s16x8*)(Ks + (f * 16 + lr) * 40 + lg * 8);
      qb[f] = *(const s16x8*)(Qs + (f * 16 + lr) * 40 + lg * 8);
    }
    f32x4 st[4][4];
#pragma unroll
    for (int fk = 0; fk < 4; ++fk)
#pragma unroll
      for (int fq = 0; fq < 4; ++fq)
        st[fk][fq] = MFMA16(ka[fk], qb[fq], (f32x4)0.0f);

    const float* bh = biasF + h * 4096;
#pragma unroll
    for (int fq = 0; fq < 4; ++fq) {
      const int q = fq * 16 + lr;
      float mx = -3.0e38f;
#pragma unroll
      for (int fk = 0; fk < 4; ++fk)
#pragma unroll
        for (int r = 0; r < 4; ++r) {
          const int kt = fk * 16 + lg * 4 + r;
          float v = st[fk][fq][r] * 0.17677669529663687f + bh[q * 64 + kt];
          st[fk][fq][r] = v;
          mx = fmaxf(mx, v);
        }
      mx = fmaxf(mx, __shfl_xor(mx, 16));
      mx = fmaxf(mx, __shfl_xor(mx, 32));
      float sm = 0.0f;
#pragma unroll
      for (int fk = 0; fk < 4; ++fk)
#pragma unroll
        for (int r = 0; r < 4; ++r) {
          float e = __expf(st[fk][fq][r] - mx);
          st[fk][fq][r] = e;
          sm += e;
        }
      sm += __shfl_xor(sm, 16);
      sm += __shfl_xor(sm, 32);
      const float inv = 1.0f / sm;
#pragma unroll
      for (int fk = 0; fk < 4; ++fk)
#pragma unroll
        for (int r = 0; r < 4; ++r) st[fk][fq][r] *= inv;
    }

    s16x8 va[2][2];
#pragma unroll
    for (int fd = 0; fd < 2; ++fd)
#pragma unroll
      for (int kb = 0; kb < 2; ++kb) {
        short4 v0 = *(const short4*)(Vts + (fd * 16 + lr) * 72 + kb * 32 + lg * 4);
        short4 v1 = *(const short4*)(Vts + (fd * 16 + lr) * 72 + kb * 32 + 16 + lg * 4);
        s16x8 tt;
        tt[0] = v0.x; tt[1] = v0.y; tt[2] = v0.z; tt[3] = v0.w;
        tt[4] = v1.x; tt[5] = v1.y; tt[6] = v1.z; tt[7] = v1.w;
        va[fd][kb] = tt;
      }
    f32x4 ot[2][4];
#pragma unroll
    for (int fd = 0; fd < 2; ++fd)
#pragma unroll
      for (int fq = 0; fq < 4; ++fq) ot[fd][fq] = (f32x4)0.0f;
#pragma unroll
    for (int kb = 0; kb < 2; ++kb)
#pragma unroll
      for (int fq = 0; fq < 4; ++fq) {
        s16x8 pb;
#pragma unroll
        for (int j = 0; j < 8; ++j)
          pb[j] = f2bf(st[2 * kb + (j >> 2)][fq][j & 3]);
#pragma unroll
        for (int fd = 0; fd < 2; ++fd)
          ot[fd][fq] = MFMA16(va[fd][kb], pb, ot[fd][fq]);
      }

#pragma unroll
    for (int fd = 0; fd < 2; ++fd)
#pragma unroll
      for (int fq = 0; fq < 4; ++fq)
#pragma unroll
        for (int r = 0; r < 4; ++r)
          Qs[(fq * 16 + lr) * 40 + fd * 16 + lg * 4 + r] = f2bf(ot[fd][fq][r]);
    short* dst = AO + ((size_t)bw * 64 + l) * 384 + h * 32;
    int4 o0 = *(const int4*)(Qs + l * 40);
    int4 o1 = *(const int4*)(Qs + l * 40 + 8);
    int4 o2 = *(const int4*)(Qs + l * 40 + 16);
    int4 o3 = *(const int4*)(Qs + l * 40 + 24);
    *(int4*)(dst)      = o0;
    *(int4*)(dst + 8)  = o1;
    *(int4*)(dst + 16) = o2;
    *(int4*)(dst + 24) = o3;
  }
}

// ---------------- output projection: out = AO(bf16) @ Wo + bo, f32 out --------
__global__ __launch_bounds__(256) void proj_kernel(
    const short* __restrict__ AO, const short* __restrict__ WoT,
    const float* __restrict__ bo, float* __restrict__ out)
{
  __shared__ short Al[128 * 72];
  __shared__ short Bl[128 * 72];
  const int bid = blockIdx.x;
  const int wg = (bid & 7) * 294 + (bid >> 3);   // XCD swizzle (2352 = 8*294)
  const int nt = wg % 3, mt = wg / 3;
  const int t = threadIdx.x;
  const int wv = t >> 6, l = t & 63, lr = l & 15, lg = l >> 4;
  const int wm = wv >> 1, wn = wv & 1;

  f32x4 acc[4][4];
#pragma unroll
  for (int fm = 0; fm < 4; ++fm)
#pragma unroll
    for (int fn = 0; fn < 4; ++fn) acc[fm][fn] = (f32x4)0.0f;

  for (int ks = 0; ks < 6; ++ks) {
    int4 av[4], bv[4];
#pragma unroll
    for (int c = 0; c < 4; ++c) {
      const int chunk = c * 256 + t;
      const int row = chunk >> 3, cc = chunk & 7;
      av[c] = *(const int4*)(AO  + (size_t)(mt * 128 + row) * 384 + ks * 64 + cc * 8);
      bv[c] = *(const int4*)(WoT + (size_t)(nt * 128 + row) * 384 + ks * 64 + cc * 8);
    }
    __syncthreads();
#pragma unroll
    for (int c = 0; c < 4; ++c) {
      const int chunk = c * 256 + t;
      const int row = chunk >> 3, cc = chunk & 7;
      *(int4*)(Al + row * 72 + cc * 8) = av[c];
      *(int4*)(Bl + row * 72 + cc * 8) = bv[c];
    }
    __syncthreads();
#pragma unroll
    for (int kk = 0; kk < 2; ++kk) {
      s16x8 af[4], bf[4];
#pragma unroll
      for (int f = 0; f < 4; ++f) {
        af[f] = *(const s16x8*)(Al + (wm * 64 + f * 16 + lr) * 72 + kk * 32 + lg * 8);
        bf[f] = *(const s16x8*)(Bl + (wn * 64 + f * 16 + lr) * 72 + kk * 32 + lg * 8);
      }
#pragma unroll
      for (int fm = 0; fm < 4; ++fm)
#pragma unroll
        for (int fn = 0; fn < 4; ++fn)
          acc[fm][fn] = MFMA16(af[fm], bf[fn], acc[fm][fn]);
    }
  }

#pragma unroll
  for (int fn = 0; fn < 4; ++fn) {
    const int n = nt * 128 + wn * 64 + fn * 16 + lr;
    const float bias = bo[n];
#pragma unroll
    for (int fm = 0; fm < 4; ++fm) {
      const int m0 = mt * 128 + wm * 64 + fm * 16 + lg * 4;
#pragma unroll
      for (int r = 0; r < 4; ++r)
        out[(size_t)(m0 + r) * 384 + n] = acc[fm][fn][r] + bias;
    }
  }
}

extern "C" void kernel_launch(void* const* d_in, const int* in_sizes, int n_in,
                              void* d_out, int out_size, void* d_ws, size_t ws_size,
                              hipStream_t stream)
{
  const float* X    = (const float*)d_in[0];
  const float* Wqkv = (const float*)d_in[1];
  const float* posb = (const float*)d_in[2];
  const float* Wo   = (const float*)d_in[3];
  const float* bo   = (const float*)d_in[4];
  const int*   relp = (const int*)d_in[5];
  float* out = (float*)d_out;

  char* ws = (char*)d_ws;
  short* WqkvT = (short*)(ws);                 //   884,736 B
  short* WoT   = (short*)(ws + 884736);        //   294,912 B
  float* biasF = (float*)(ws + 1179648);       //   196,608 B

  const size_t NEED_SPLIT = 309657600ull;
  prep_kernel<<<2496, 256, 0, stream>>>(Wqkv, Wo, posb, relp, WqkvT, WoT, biasF);

  if (ws_size >= NEED_SPLIT) {
    short* Qb  = (short*)(ws + 1376256);       // 77,070,336 B [win][12][64][32]
    short* Kb  = (short*)(ws + 78446592);      // 77,070,336 B [win][12][64][32]
    short* Vtb = (short*)(ws + 155516928);     // 77,070,336 B [win][12][32][64]
    short* AO  = (short*)(ws + 232587264);     // 77,070,336 B [100352][384]
    qkv_gemm<<<7056, 256, 0, stream>>>(X, WqkvT, Qb, Kb, Vtb);
    attn_split<<<4704, 256, 0, stream>>>(Qb, Kb, Vtb, biasF, AO);
    proj_kernel<<<2352, 256, 0, stream>>>(AO, WoT, bo, out);
  } else {
    short* AO = (short*)(ws + 1376256);        // 77,070,336 B
    attn_fused<<<1568, 256, 0, stream>>>(X, WqkvT, biasF, AO);
    proj_kernel<<<2352, 256, 0, stream>>>(AO, WoT, bo, out);
  }
}

// Round 3
// 361.187 us; speedup vs baseline: 1.8027x; 1.5820x over previous
//
#include <hip/hip_runtime.h>

typedef float f32x4 __attribute__((ext_vector_type(4)));
typedef short s16x8 __attribute__((ext_vector_type(8)));

#define MFMA16(A,B,C) __builtin_amdgcn_mfma_f32_16x16x32_bf16((A),(B),(C),0,0,0)

__device__ __forceinline__ short f2bf(float f) {
  union { float f; unsigned u; } v; v.f = f;
  unsigned r = v.u + 0x7FFFu + ((v.u >> 16) & 1u);   // RNE
  return (short)(r >> 16);
}

__device__ __forceinline__ void gload_lds16(const void* g, void* l) {
  __builtin_amdgcn_global_load_lds(
      (const __attribute__((address_space(1))) unsigned*)g,
      (__attribute__((address_space(3))) unsigned*)l, 16, 0, 0);
}

// ---------------- prep: transpose weights to bf16[N][K], gather bias table ----
__global__ __launch_bounds__(256) void prep_kernel(
    const float* __restrict__ Wqkv, const float* __restrict__ Wo,
    const float* __restrict__ posb, const int* __restrict__ relp,
    short* __restrict__ WqkvT, short* __restrict__ WoT, float* __restrict__ biasF)
{
  int i = blockIdx.x * 256 + threadIdx.x;
  if (i < 1152 * 384) {
    int n = i / 384, k = i % 384;
    WqkvT[i] = f2bf(Wqkv[k * 1152 + n]);
  } else if (i < 1152 * 384 + 384 * 384) {
    int j = i - 1152 * 384;
    int n = j / 384, k = j % 384;
    WoT[j] = f2bf(Wo[k * 384 + n]);
  } else {
    int j = i - (1152 * 384 + 384 * 384);    // j < 12*64*64 = 49152
    int h = j >> 12, qk = j & 4095;
    biasF[j] = posb[h * 16129 + relp[qk]];
  }
}

// ---------------- X f32 -> bf16 (memory-bound, vectorized) --------------------
__global__ __launch_bounds__(256) void xcvt_kernel(
    const float* __restrict__ X, short* __restrict__ Xbf)
{
  const int n8 = 4816896;                  // 38,535,168 / 8
  for (int i = blockIdx.x * 256 + threadIdx.x; i < n8; i += gridDim.x * 256) {
    float4 a = *(const float4*)(X + (size_t)i * 8);
    float4 b = *(const float4*)(X + (size_t)i * 8 + 4);
    s16x8 p;
    p[0] = f2bf(a.x); p[1] = f2bf(a.y); p[2] = f2bf(a.z); p[3] = f2bf(a.w);
    p[4] = f2bf(b.x); p[5] = f2bf(b.y); p[6] = f2bf(b.z); p[7] = f2bf(b.w);
    *(s16x8*)(Xbf + (size_t)i * 8) = p;
  }
}

// ---------------- QKV GEMM: Xbf(100352x384) @ WqkvT^T -> Q/K/Vt bf16 ----------
// 128x128 tile, 4 waves 2x2, BK=64. Both operands via global_load_lds into
// linear [128][64] LDS; XOR-chunk involution (chunk ^= row&7) applied on the
// global SOURCE address and again on the ds_read — G4/rule#21.
__global__ __launch_bounds__(256) void qkv_gemm(
    const short* __restrict__ Xbf, const short* __restrict__ WqkvT,
    short* __restrict__ Qb, short* __restrict__ Kb, short* __restrict__ Vtb)
{
  __shared__ short lds[17408];           // A: [0,8192) B: [8192,16384) shorts
  const int bid = blockIdx.x;
  const int wg = (bid & 7) * 882 + (bid >> 3);   // XCD swizzle (7056 = 8*882)
  const int nt = wg % 9, mt = wg / 9;
  const int t = threadIdx.x;
  const int wv = t >> 6, l = t & 63, lr = l & 15, lg = l >> 4;
  const int wm = wv >> 1, wn = wv & 1;

  f32x4 acc[4][4];
#pragma unroll
  for (int fm = 0; fm < 4; ++fm)
#pragma unroll
    for (int fn = 0; fn < 4; ++fn) acc[fm][fn] = (f32x4)0.0f;

  // per-lane source row/chunk for the 4 staging instructions of this wave
  // instr i covers rows wv*32 + i*8 + (l>>3), chunk c = l&7 (linear LDS),
  // global chunk = c ^ (row&7)
  const int srow = wv * 32 + (l >> 3);
  const int sc = l & 7;

  for (int ks = 0; ks < 6; ++ks) {
    __syncthreads();                     // previous compute done, LDS free
#pragma unroll
    for (int i = 0; i < 4; ++i) {
      const int row = srow + i * 8;
      const int cg = sc ^ (row & 7);
      gload_lds16(Xbf + (size_t)(mt * 128 + row) * 384 + ks * 64 + cg * 8,
                  lds + (wv * 4 + i) * 512);
      gload_lds16(WqkvT + (size_t)(nt * 128 + row) * 384 + ks * 64 + cg * 8,
                  lds + 8192 + (wv * 4 + i) * 512);
    }
    __syncthreads();                     // drains vmcnt -> tiles ready

#pragma unroll
    for (int kk = 0; kk < 2; ++kk) {
      s16x8 af[4], bf[4];
#pragma unroll
      for (int f = 0; f < 4; ++f) {
        const int arow = wm * 64 + f * 16 + lr;
        const int ac = (kk * 4 + lg) ^ (arow & 7);
        af[f] = *(const s16x8*)(lds + arow * 64 + ac * 8);
        const int brow = wn * 64 + f * 16 + lr;
        const int bc = (kk * 4 + lg) ^ (brow & 7);
        bf[f] = *(const s16x8*)(lds + 8192 + brow * 64 + bc * 8);
      }
#pragma unroll
      for (int fm = 0; fm < 4; ++fm)
#pragma unroll
        for (int fn = 0; fn < 4; ++fn)
          acc[fm][fn] = MFMA16(af[fm], bf[fn], acc[fm][fn]);
    }
  }

  // ---- epilogue ----
  const int sel = nt / 3, hq = (nt % 3) * 4;
  if (sel == 2) {
    // V: direct transposed stores Vt[win][h][d][tok]
#pragma unroll
    for (int fm = 0; fm < 4; ++fm)
#pragma unroll
      for (int fn = 0; fn < 4; ++fn) {
        const int m0 = wm * 64 + fm * 16 + lg * 4;
        const int win = m0 >> 6, tok0 = m0 & 63;
        const int n = wn * 64 + fn * 16 + lr;
        const int hl = n >> 5, d = n & 31;
        short4 v;
        v.x = f2bf(acc[fm][fn][0]); v.y = f2bf(acc[fm][fn][1]);
        v.z = f2bf(acc[fm][fn][2]); v.w = f2bf(acc[fm][fn][3]);
        *(short4*)(Vtb + (size_t)(mt * 2 + win) * 24576 + (hq + hl) * 2048
                   + d * 64 + tok0) = v;
      }
  } else {
    // Q/K: re-stage tile in LDS [128][136], then coalesced 64B row writes
    __syncthreads();
    short* Cl = lds;     // 128*136 = 17408 shorts, exactly fits
#pragma unroll
    for (int fm = 0; fm < 4; ++fm)
#pragma unroll
      for (int fn = 0; fn < 4; ++fn)
#pragma unroll
        for (int r = 0; r < 4; ++r)
          Cl[(wm * 64 + fm * 16 + lg * 4 + r) * 136 + wn * 64 + fn * 16 + lr] =
              f2bf(acc[fm][fn][r]);
    __syncthreads();
    short* dst0 = (sel ? Kb : Qb) + (size_t)mt * 2 * 24576;
#pragma unroll
    for (int rr = 0; rr < 2; ++rr) {
      const int ro = t * 2 + rr;
      const int win = ro >> 8, hl = (ro >> 6) & 3, tok = ro & 63;
      const int m = win * 64 + tok;
      const short* srcl = Cl + m * 136 + hl * 32;
      int4 a0 = *(const int4*)(srcl);
      int4 a1 = *(const int4*)(srcl + 8);
      int4 a2 = *(const int4*)(srcl + 16);
      int4 a3 = *(const int4*)(srcl + 24);
      short* dp = dst0 + win * 24576 + (hq + hl) * 2048 + tok * 32;
      *(int4*)(dp)      = a0;
      *(int4*)(dp + 8)  = a1;
      *(int4*)(dp + 16) = a2;
      *(int4*)(dp + 24) = a3;
    }
  }
}

// ---------------- attention: one wave per (window, head) ----------------------
__global__ __launch_bounds__(256) void attn_split(
    const short* __restrict__ Qb, const short* __restrict__ Kb,
    const short* __restrict__ Vtb, const float* __restrict__ biasF,
    short* __restrict__ AO)
{
  __shared__ short obuf[10240];          // 4 waves * [64][40]
  const int bid = blockIdx.x;
  const int wg = (bid & 7) * 588 + (bid >> 3);   // XCD swizzle (4704 = 8*588)
  const int wv = threadIdx.x >> 6;
  const int l = threadIdx.x & 63, lr = l & 15, lg = l >> 4;
  const int p = wg * 4 + wv;                     // (w,h) pair, p = w*12 + h
  const int w = p / 12, h = p % 12;

  const short* Kp = Kb + (size_t)p * 2048;
  const short* Qp = Qb + (size_t)p * 2048;
  const short* Vp = Vtb + (size_t)p * 2048;
  const float* bh = biasF + h * 4096;

  // fragment loads straight from global (already in MFMA layout)
  s16x8 ka[4], qf[4];
#pragma unroll
  for (int f = 0; f < 4; ++f) {
    ka[f] = *(const s16x8*)(Kp + (f * 16 + lr) * 32 + lg * 8);
    qf[f] = *(const s16x8*)(Qp + (f * 16 + lr) * 32 + lg * 8);
  }
  s16x8 va[2][2];
#pragma unroll
  for (int fd = 0; fd < 2; ++fd)
#pragma unroll
    for (int kb = 0; kb < 2; ++kb) {
      short4 v0 = *(const short4*)(Vp + (fd * 16 + lr) * 64 + kb * 32 + lg * 4);
      short4 v1 = *(const short4*)(Vp + (fd * 16 + lr) * 64 + kb * 32 + 16 + lg * 4);
      s16x8 tv;
      tv[0] = v0.x; tv[1] = v0.y; tv[2] = v0.z; tv[3] = v0.w;
      tv[4] = v1.x; tv[5] = v1.y; tv[6] = v1.z; tv[7] = v1.w;
      va[fd][kb] = tv;
    }

  // S^T = K·Q^T  (rows kt, cols q), K-dim 32
  f32x4 st[4][4];
#pragma unroll
  for (int fk = 0; fk < 4; ++fk)
#pragma unroll
    for (int fq = 0; fq < 4; ++fq)
      st[fk][fq] = MFMA16(ka[fk], qf[fq], (f32x4)0.0f);

  // scale + bias + softmax over kt (per q column, per-lane + shfl 16/32)
#pragma unroll
  for (int fq = 0; fq < 4; ++fq) {
    const int q = fq * 16 + lr;
    float4 bv[4];
#pragma unroll
    for (int fk = 0; fk < 4; ++fk)
      bv[fk] = *(const float4*)(bh + q * 64 + fk * 16 + lg * 4);
    float mx = -3.0e38f;
#pragma unroll
    for (int fk = 0; fk < 4; ++fk)
#pragma unroll
      for (int r = 0; r < 4; ++r) {
        float v = st[fk][fq][r] * 0.17677669529663687f + ((const float*)&bv[fk])[r];
        st[fk][fq][r] = v;
        mx = fmaxf(mx, v);
      }
    mx = fmaxf(mx, __shfl_xor(mx, 16));
    mx = fmaxf(mx, __shfl_xor(mx, 32));
    float sm = 0.0f;
#pragma unroll
    for (int fk = 0; fk < 4; ++fk)
#pragma unroll
      for (int r = 0; r < 4; ++r) {
        float e = __expf(st[fk][fq][r] - mx);
        st[fk][fq][r] = e;
        sm += e;
      }
    sm += __shfl_xor(sm, 16);
    sm += __shfl_xor(sm, 32);
    const float inv = 1.0f / sm;
#pragma unroll
    for (int fk = 0; fk < 4; ++fk)
#pragma unroll
      for (int r = 0; r < 4; ++r) st[fk][fq][r] *= inv;
  }

  // O^T = V^T · P^T ; sigma(g,j)=32kb+16(j>>2)+4g+(j&3) on both operands
  f32x4 ot[2][4];
#pragma unroll
  for (int fd = 0; fd < 2; ++fd)
#pragma unroll
    for (int fq = 0; fq < 4; ++fq) ot[fd][fq] = (f32x4)0.0f;
#pragma unroll
  for (int kb = 0; kb < 2; ++kb)
#pragma unroll
    for (int fq = 0; fq < 4; ++fq) {
      s16x8 pb;
#pragma unroll
      for (int j = 0; j < 8; ++j)
        pb[j] = f2bf(st[2 * kb + (j >> 2)][fq][j & 3]);   // lane-local repack
#pragma unroll
      for (int fd = 0; fd < 2; ++fd)
        ot[fd][fq] = MFMA16(va[fd][kb], pb, ot[fd][fq]);
    }

  // epilogue: stage [q][d] per-wave in LDS, write coalesced 16B rows
  short* ob = obuf + wv * 2560;
#pragma unroll
  for (int fd = 0; fd < 2; ++fd)
#pragma unroll
    for (int fq = 0; fq < 4; ++fq)
#pragma unroll
      for (int r = 0; r < 4; ++r)
        ob[(fq * 16 + lr) * 40 + fd * 16 + lg * 4 + r] = f2bf(ot[fd][fq][r]);
  short* dst = AO + ((size_t)w * 64 + l) * 384 + h * 32;
  int4 o0 = *(const int4*)(ob + l * 40);
  int4 o1 = *(const int4*)(ob + l * 40 + 8);
  int4 o2 = *(const int4*)(ob + l * 40 + 16);
  int4 o3 = *(const int4*)(ob + l * 40 + 24);
  *(int4*)(dst)      = o0;
  *(int4*)(dst + 8)  = o1;
  *(int4*)(dst + 16) = o2;
  *(int4*)(dst + 24) = o3;
}

// ---------------- output projection: out = AO(bf16) @ Wo + bo, f32 out --------
// Same gload_lds + XOR-involution staging as qkv_gemm.
__global__ __launch_bounds__(256) void proj_kernel(
    const short* __restrict__ AO, const short* __restrict__ WoT,
    const float* __restrict__ bo, float* __restrict__ out)
{
  __shared__ short lds[16384];           // A: [0,8192) B: [8192,16384)
  const int bid = blockIdx.x;
  const int wg = (bid & 7) * 294 + (bid >> 3);   // XCD swizzle (2352 = 8*294)
  const int nt = wg % 3, mt = wg / 3;
  const int t = threadIdx.x;
  const int wv = t >> 6, l = t & 63, lr = l & 15, lg = l >> 4;
  const int wm = wv >> 1, wn = wv & 1;

  f32x4 acc[4][4];
#pragma unroll
  for (int fm = 0; fm < 4; ++fm)
#pragma unroll
    for (int fn = 0; fn < 4; ++fn) acc[fm][fn] = (f32x4)0.0f;

  const int srow = wv * 32 + (l >> 3);
  const int sc = l & 7;

  for (int ks = 0; ks < 6; ++ks) {
    __syncthreads();
#pragma unroll
    for (int i = 0; i < 4; ++i) {
      const int row = srow + i * 8;
      const int cg = sc ^ (row & 7);
      gload_lds16(AO  + (size_t)(mt * 128 + row) * 384 + ks * 64 + cg * 8,
                  lds + (wv * 4 + i) * 512);
      gload_lds16(WoT + (size_t)(nt * 128 + row) * 384 + ks * 64 + cg * 8,
                  lds + 8192 + (wv * 4 + i) * 512);
    }
    __syncthreads();

#pragma unroll
    for (int kk = 0; kk < 2; ++kk) {
      s16x8 af[4], bf[4];
#pragma unroll
      for (int f = 0; f < 4; ++f) {
        const int arow = wm * 64 + f * 16 + lr;
        const int ac = (kk * 4 + lg) ^ (arow & 7);
        af[f] = *(const s16x8*)(lds + arow * 64 + ac * 8);
        const int brow = wn * 64 + f * 16 + lr;
        const int bc = (kk * 4 + lg) ^ (brow & 7);
        bf[f] = *(const s16x8*)(lds + 8192 + brow * 64 + bc * 8);
      }
#pragma unroll
      for (int fm = 0; fm < 4; ++fm)
#pragma unroll
        for (int fn = 0; fn < 4; ++fn)
          acc[fm][fn] = MFMA16(af[fm], bf[fn], acc[fm][fn]);
    }
  }

#pragma unroll
  for (int fn = 0; fn < 4; ++fn) {
    const int n = nt * 128 + wn * 64 + fn * 16 + lr;
    const float bias = bo[n];
#pragma unroll
    for (int fm = 0; fm < 4; ++fm) {
      const int m0 = mt * 128 + wm * 64 + fm * 16 + lg * 4;
#pragma unroll
      for (int r = 0; r < 4; ++r)
        out[(size_t)(m0 + r) * 384 + n] = acc[fm][fn][r] + bias;
    }
  }
}

extern "C" void kernel_launch(void* const* d_in, const int* in_sizes, int n_in,
                              void* d_out, int out_size, void* d_ws, size_t ws_size,
                              hipStream_t stream)
{
  const float* X    = (const float*)d_in[0];
  const float* Wqkv = (const float*)d_in[1];
  const float* posb = (const float*)d_in[2];
  const float* Wo   = (const float*)d_in[3];
  const float* bo   = (const float*)d_in[4];
  const int*   relp = (const int*)d_in[5];
  float* out = (float*)d_out;

  // workspace carve — total 309,657,600 B (proven available in round 2)
  char* ws = (char*)d_ws;
  short* WqkvT = (short*)(ws);                 //   884,736 B
  short* WoT   = (short*)(ws + 884736);        //   294,912 B
  float* biasF = (float*)(ws + 1179648);       //   196,608 B
  short* XbfAO = (short*)(ws + 1376256);       // 77,070,336 B : Xbf, then AO
  short* Qb    = (short*)(ws + 78446592);      // 77,070,336 B [win][12][64][32]
  short* Kb    = (short*)(ws + 155516928);     // 77,070,336 B [win][12][64][32]
  short* Vtb   = (short*)(ws + 232587264);     // 77,070,336 B [win][12][32][64]

  prep_kernel<<<2496, 256, 0, stream>>>(Wqkv, Wo, posb, relp, WqkvT, WoT, biasF);
  xcvt_kernel<<<2048, 256, 0, stream>>>(X, XbfAO);
  qkv_gemm<<<7056, 256, 0, stream>>>(XbfAO, WqkvT, Qb, Kb, Vtb);
  // Xbf is dead after qkv_gemm; attn_split reuses the region as AO
  attn_split<<<4704, 256, 0, stream>>>(Qb, Kb, Vtb, biasF, XbfAO);
  proj_kernel<<<2352, 256, 0, stream>>>(XbfAO, WoT, bo, out);
}

// Round 5
// 332.323 us; speedup vs baseline: 1.9592x; 1.0869x over previous
//
#include <hip/hip_runtime.h>

typedef float f32x4 __attribute__((ext_vector_type(4)));
typedef short s16x8 __attribute__((ext_vector_type(8)));

#define MFMA16(A,B,C) __builtin_amdgcn_mfma_f32_16x16x32_bf16((A),(B),(C),0,0,0)

__device__ __forceinline__ short f2bf(float f) {
  union { float f; unsigned u; } v; v.f = f;
  unsigned r = v.u + 0x7FFFu + ((v.u >> 16) & 1u);   // RNE
  return (short)(r >> 16);
}

__device__ __forceinline__ void gload_lds16(const void* g, void* l) {
  __builtin_amdgcn_global_load_lds(
      (const __attribute__((address_space(1))) unsigned*)g,
      (__attribute__((address_space(3))) unsigned*)l, 16, 0, 0);
}

// ---------------- prep: transpose weights to bf16[N][K], gather bias table ----
__global__ __launch_bounds__(256) void prep_kernel(
    const float* __restrict__ Wqkv, const float* __restrict__ Wo,
    const float* __restrict__ posb, const int* __restrict__ relp,
    short* __restrict__ WqkvT, short* __restrict__ WoT, float* __restrict__ biasF)
{
  int i = blockIdx.x * 256 + threadIdx.x;
  if (i < 1152 * 384) {
    int n = i / 384, k = i % 384;
    WqkvT[i] = f2bf(Wqkv[k * 1152 + n]);
  } else if (i < 1152 * 384 + 384 * 384) {
    int j = i - 1152 * 384;
    int n = j / 384, k = j % 384;
    WoT[j] = f2bf(Wo[k * 384 + n]);
  } else {
    int j = i - (1152 * 384 + 384 * 384);    // j < 12*64*64 = 49152
    int h = j >> 12, qk = j & 4095;
    biasF[j] = posb[h * 16129 + relp[qk]];
  }
}

// ---------------- X f32 -> bf16 (memory-bound, vectorized) --------------------
__global__ __launch_bounds__(256) void xcvt_kernel(
    const float* __restrict__ X, short* __restrict__ Xbf)
{
  const int n8 = 4816896;                  // 38,535,168 / 8
  for (int i = blockIdx.x * 256 + threadIdx.x; i < n8; i += gridDim.x * 256) {
    float4 a = *(const float4*)(X + (size_t)i * 8);
    float4 b = *(const float4*)(X + (size_t)i * 8 + 4);
    s16x8 p;
    p[0] = f2bf(a.x); p[1] = f2bf(a.y); p[2] = f2bf(a.z); p[3] = f2bf(a.w);
    p[4] = f2bf(b.x); p[5] = f2bf(b.y); p[6] = f2bf(b.z); p[7] = f2bf(b.w);
    *(s16x8*)(Xbf + (size_t)i * 8) = p;
  }
}

// ---------------- QKV GEMM: Xbf(100352x384) @ WqkvT^T -> Q/K/Vt bf16 ----------
// 128x128 tile, 4 waves 2x2, BK=64, double-buffered T3 minimum-2-phase:
//   STAGE(t+1, other half) issued BEFORE compute(t); __syncthreads() at end
//   of iter drains vmcnt (stage) + lgkmcnt (ds_reads) -> no WAR race (the R4
//   raw-barrier form raced per rule #18; syncthreads form is watertight).
// XOR-chunk involution on source + ds_read (rule #21) unchanged from R3.
__global__ __launch_bounds__(256) void qkv_gemm(
    const short* __restrict__ Xbf, const short* __restrict__ WqkvT,
    short* __restrict__ Qb, short* __restrict__ Kb, short* __restrict__ Vtb)
{
  __shared__ short lds[32768];   // half sel: A @ sel*16384, B @ sel*16384+8192
  const int bid = blockIdx.x;
  const int wg = (bid & 7) * 882 + (bid >> 3);   // XCD swizzle (7056 = 8*882)
  const int nt = wg % 9, mt = wg / 9;
  const int t = threadIdx.x;
  const int wv = t >> 6, l = t & 63, lr = l & 15, lg = l >> 4;
  const int wm = wv >> 1, wn = wv & 1;

  f32x4 acc[4][4];
#pragma unroll
  for (int fm = 0; fm < 4; ++fm)
#pragma unroll
    for (int fn = 0; fn < 4; ++fn) acc[fm][fn] = (f32x4)0.0f;

  const int srow = wv * 32 + (l >> 3);
  const int cg = (l & 7) ^ (srow & 7);           // srow+8i keeps (row&7) const
  const short* Ab = Xbf   + (size_t)(mt * 128 + srow) * 384 + cg * 8;
  const short* Bb = WqkvT + (size_t)(nt * 128 + srow) * 384 + cg * 8;

#define STAGE_QKV(KS, SEL) do {                                              \
  _Pragma("unroll")                                                          \
  for (int i_ = 0; i_ < 4; ++i_) {                                           \
    gload_lds16(Ab + i_ * 3072 + (KS) * 64,                                  \
                lds + (SEL) * 16384 + (wv * 4 + i_) * 512);                  \
    gload_lds16(Bb + i_ * 3072 + (KS) * 64,                                  \
                lds + (SEL) * 16384 + 8192 + (wv * 4 + i_) * 512);           \
  } } while (0)

  STAGE_QKV(0, 0);
  __syncthreads();                       // tile 0 landed (vmcnt0 + barrier)
  for (int ks = 0; ks < 6; ++ks) {
    const int cur = ks & 1;
    if (ks < 5) STAGE_QKV(ks + 1, cur ^ 1);   // overlaps compute below
    const short* Acur = lds + cur * 16384;
    const short* Bcur = Acur + 8192;
#pragma unroll
    for (int kk = 0; kk < 2; ++kk) {
      s16x8 af[4], bf[4];
#pragma unroll
      for (int f = 0; f < 4; ++f) {
        const int arow = wm * 64 + f * 16 + lr;
        const int ac = (kk * 4 + lg) ^ (arow & 7);
        af[f] = *(const s16x8*)(Acur + arow * 64 + ac * 8);
        const int brow = wn * 64 + f * 16 + lr;
        const int bc = (kk * 4 + lg) ^ (brow & 7);
        bf[f] = *(const s16x8*)(Bcur + brow * 64 + bc * 8);
      }
#pragma unroll
      for (int fm = 0; fm < 4; ++fm)
#pragma unroll
        for (int fn = 0; fn < 4; ++fn)
          acc[fm][fn] = MFMA16(af[fm], bf[fn], acc[fm][fn]);
    }
    __syncthreads();                     // drain stage (vm) + reads (lgkm)
  }
#undef STAGE_QKV

  // ---- epilogue ----
  const int sel = nt / 3, hq = (nt % 3) * 4;
  if (sel == 2) {
    // V: direct transposed stores Vt[win][h][d][tok] (R3-proven path)
#pragma unroll
    for (int fm = 0; fm < 4; ++fm)
#pragma unroll
      for (int fn = 0; fn < 4; ++fn) {
        const int m0 = wm * 64 + fm * 16 + lg * 4;
        const int win = m0 >> 6, tok0 = m0 & 63;
        const int n = wn * 64 + fn * 16 + lr;
        const int hl = n >> 5, d = n & 31;
        short4 v;
        v.x = f2bf(acc[fm][fn][0]); v.y = f2bf(acc[fm][fn][1]);
        v.z = f2bf(acc[fm][fn][2]); v.w = f2bf(acc[fm][fn][3]);
        *(short4*)(Vtb + (size_t)(mt * 2 + win) * 24576 + (hq + hl) * 2048
                   + d * 64 + tok0) = v;
      }
  } else {
    // Q/K: re-stage tile in LDS (stride 138, bank-coprime), coalesced writes
    short* Cl = lds;                     // 128*138 = 17664 shorts, fits
#pragma unroll
    for (int fm = 0; fm < 4; ++fm)
#pragma unroll
      for (int fn = 0; fn < 4; ++fn)
#pragma unroll
        for (int r = 0; r < 4; ++r)
          Cl[(wm * 64 + fm * 16 + lg * 4 + r) * 138 + wn * 64 + fn * 16 + lr] =
              f2bf(acc[fm][fn][r]);
    __syncthreads();
    short* dst0 = (sel ? Kb : Qb) + (size_t)mt * 2 * 24576;
#pragma unroll
    for (int rr = 0; rr < 2; ++rr) {
      const int ro = t * 2 + rr;
      const int win = ro >> 8, hl = (ro >> 6) & 3, tok = ro & 63;
      const int m = win * 64 + tok;
      const short* srcl = Cl + m * 138 + hl * 32;
      int4 a0 = *(const int4*)(srcl);
      int4 a1 = *(const int4*)(srcl + 8);
      int4 a2 = *(const int4*)(srcl + 16);
      int4 a3 = *(const int4*)(srcl + 24);
      short* dp = dst0 + win * 24576 + (hq + hl) * 2048 + tok * 32;
      *(int4*)(dp)      = a0;
      *(int4*)(dp + 8)  = a1;
      *(int4*)(dp + 16) = a2;
      *(int4*)(dp + 24) = a3;
    }
  }
}

// ---------------- attention: one wave per (window, head) ----------------------
__global__ __launch_bounds__(256) void attn_split(
    const short* __restrict__ Qb, const short* __restrict__ Kb,
    const short* __restrict__ Vtb, const float* __restrict__ biasF,
    short* __restrict__ AO)
{
  __shared__ short obuf[10240];          // 4 waves * [64][40]
  const int bid = blockIdx.x;
  const int wg = (bid & 7) * 588 + (bid >> 3);   // XCD swizzle (4704 = 8*588)
  const int wv = threadIdx.x >> 6;
  const int l = threadIdx.x & 63, lr = l & 15, lg = l >> 4;
  const int p = wg * 4 + wv;                     // (w,h) pair, p = w*12 + h
  const int w = p / 12, h = p % 12;

  const short* Kp = Kb + (size_t)p * 2048;
  const short* Qp = Qb + (size_t)p * 2048;
  const short* Vp = Vtb + (size_t)p * 2048;
  const float* bh = biasF + h * 4096;

  s16x8 ka[4], qf[4];
#pragma unroll
  for (int f = 0; f < 4; ++f) {
    ka[f] = *(const s16x8*)(Kp + (f * 16 + lr) * 32 + lg * 8);
    qf[f] = *(const s16x8*)(Qp + (f * 16 + lr) * 32 + lg * 8);
  }
  s16x8 va[2][2];
#pragma unroll
  for (int fd = 0; fd < 2; ++fd)
#pragma unroll
    for (int kb = 0; kb < 2; ++kb) {
      short4 v0 = *(const short4*)(Vp + (fd * 16 + lr) * 64 + kb * 32 + lg * 4);
      short4 v1 = *(const short4*)(Vp + (fd * 16 + lr) * 64 + kb * 32 + 16 + lg * 4);
      s16x8 tv;
      tv[0] = v0.x; tv[1] = v0.y; tv[2] = v0.z; tv[3] = v0.w;
      tv[4] = v1.x; tv[5] = v1.y; tv[6] = v1.z; tv[7] = v1.w;
      va[fd][kb] = tv;
    }

  // S^T = K·Q^T  (rows kt, cols q), K-dim 32
  f32x4 st[4][4];
#pragma unroll
  for (int fk = 0; fk < 4; ++fk)
#pragma unroll
    for (int fq = 0; fq < 4; ++fq)
      st[fk][fq] = MFMA16(ka[fk], qf[fq], (f32x4)0.0f);

  // scale + bias + softmax over kt (per q column, per-lane + shfl 16/32)
#pragma unroll
  for (int fq = 0; fq < 4; ++fq) {
    const int q = fq * 16 + lr;
    float4 bv[4];
#pragma unroll
    for (int fk = 0; fk < 4; ++fk)
      bv[fk] = *(const float4*)(bh + q * 64 + fk * 16 + lg * 4);
    float mx = -3.0e38f;
#pragma unroll
    for (int fk = 0; fk < 4; ++fk)
#pragma unroll
      for (int r = 0; r < 4; ++r) {
        float v = st[fk][fq][r] * 0.17677669529663687f + ((const float*)&bv[fk])[r];
        st[fk][fq][r] = v;
        mx = fmaxf(mx, v);
      }
    mx = fmaxf(mx, __shfl_xor(mx, 16));
    mx = fmaxf(mx, __shfl_xor(mx, 32));
    float sm = 0.0f;
#pragma unroll
    for (int fk = 0; fk < 4; ++fk)
#pragma unroll
      for (int r = 0; r < 4; ++r) {
        float e = __expf(st[fk][fq][r] - mx);
        st[fk][fq][r] = e;
        sm += e;
      }
    sm += __shfl_xor(sm, 16);
    sm += __shfl_xor(sm, 32);
    const float inv = 1.0f / sm;
#pragma unroll
    for (int fk = 0; fk < 4; ++fk)
#pragma unroll
      for (int r = 0; r < 4; ++r) st[fk][fq][r] *= inv;
  }

  // O^T = V^T · P^T ; sigma(g,j)=32kb+16(j>>2)+4g+(j&3) on both operands
  f32x4 ot[2][4];
#pragma unroll
  for (int fd = 0; fd < 2; ++fd)
#pragma unroll
    for (int fq = 0; fq < 4; ++fq) ot[fd][fq] = (f32x4)0.0f;
#pragma unroll
  for (int kb = 0; kb < 2; ++kb)
#pragma unroll
    for (int fq = 0; fq < 4; ++fq) {
      s16x8 pb;
#pragma unroll
      for (int j = 0; j < 8; ++j)
        pb[j] = f2bf(st[2 * kb + (j >> 2)][fq][j & 3]);   // lane-local repack
#pragma unroll
      for (int fd = 0; fd < 2; ++fd)
        ot[fd][fq] = MFMA16(va[fd][kb], pb, ot[fd][fq]);
    }

  // epilogue: stage [q][d] per-wave in LDS, write coalesced 16B rows
  short* ob = obuf + wv * 2560;
#pragma unroll
  for (int fd = 0; fd < 2; ++fd)
#pragma unroll
    for (int fq = 0; fq < 4; ++fq)
#pragma unroll
      for (int r = 0; r < 4; ++r)
        ob[(fq * 16 + lr) * 40 + fd * 16 + lg * 4 + r] = f2bf(ot[fd][fq][r]);
  short* dst = AO + ((size_t)w * 64 + l) * 384 + h * 32;
  int4 o0 = *(const int4*)(ob + l * 40);
  int4 o1 = *(const int4*)(ob + l * 40 + 8);
  int4 o2 = *(const int4*)(ob + l * 40 + 16);
  int4 o3 = *(const int4*)(ob + l * 40 + 24);
  *(int4*)(dst)      = o0;
  *(int4*)(dst + 8)  = o1;
  *(int4*)(dst + 16) = o2;
  *(int4*)(dst + 24) = o3;
}

// ---------------- output projection: out = AO(bf16) @ Wo + bo, f32 out --------
// Same double-buffered T3 2-phase pipeline as qkv_gemm.
__global__ __launch_bounds__(256) void proj_kernel(
    const short* __restrict__ AO, const short* __restrict__ WoT,
    const float* __restrict__ bo, float* __restrict__ out)
{
  __shared__ short lds[32768];
  const int bid = blockIdx.x;
  const int wg = (bid & 7) * 294 + (bid >> 3);   // XCD swizzle (2352 = 8*294)
  const int nt = wg % 3, mt = wg / 3;
  const int t = threadIdx.x;
  const int wv = t >> 6, l = t & 63, lr = l & 15, lg = l >> 4;
  const int wm = wv >> 1, wn = wv & 1;

  f32x4 acc[4][4];
#pragma unroll
  for (int fm = 0; fm < 4; ++fm)
#pragma unroll
    for (int fn = 0; fn < 4; ++fn) acc[fm][fn] = (f32x4)0.0f;

  const int srow = wv * 32 + (l >> 3);
  const int cg = (l & 7) ^ (srow & 7);
  const short* Ab = AO  + (size_t)(mt * 128 + srow) * 384 + cg * 8;
  const short* Bb = WoT + (size_t)(nt * 128 + srow) * 384 + cg * 8;

#define STAGE_PRJ(KS, SEL) do {                                              \
  _Pragma("unroll")                                                          \
  for (int i_ = 0; i_ < 4; ++i_) {                                           \
    gload_lds16(Ab + i_ * 3072 + (KS) * 64,                                  \
                lds + (SEL) * 16384 + (wv * 4 + i_) * 512);                  \
    gload_lds16(Bb + i_ * 3072 + (KS) * 64,                                  \
                lds + (SEL) * 16384 + 8192 + (wv * 4 + i_) * 512);           \
  } } while (0)

  STAGE_PRJ(0, 0);
  __syncthreads();
  for (int ks = 0; ks < 6; ++ks) {
    const int cur = ks & 1;
    if (ks < 5) STAGE_PRJ(ks + 1, cur ^ 1);
    const short* Acur = lds + cur * 16384;
    const short* Bcur = Acur + 8192;
#pragma unroll
    for (int kk = 0; kk < 2; ++kk) {
      s16x8 af[4], bf[4];
#pragma unroll
      for (int f = 0; f < 4; ++f) {
        const int arow = wm * 64 + f * 16 + lr;
        const int ac = (kk * 4 + lg) ^ (arow & 7);
        af[f] = *(const s16x8*)(Acur + arow * 64 + ac * 8);
        const int brow = wn * 64 + f * 16 + lr;
        const int bc = (kk * 4 + lg) ^ (brow & 7);
        bf[f] = *(const s16x8*)(Bcur + brow * 64 + bc * 8);
      }
#pragma unroll
      for (int fm = 0; fm < 4; ++fm)
#pragma unroll
        for (int fn = 0; fn < 4; ++fn)
          acc[fm][fn] = MFMA16(af[fm], bf[fn], acc[fm][fn]);
    }
    __syncthreads();
  }
#undef STAGE_PRJ

#pragma unroll
  for (int fn = 0; fn < 4; ++fn) {
    const int n = nt * 128 + wn * 64 + fn * 16 + lr;
    const float bias = bo[n];
#pragma unroll
    for (int fm = 0; fm < 4; ++fm) {
      const int m0 = mt * 128 + wm * 64 + fm * 16 + lg * 4;
#pragma unroll
      for (int r = 0; r < 4; ++r)
        out[(size_t)(m0 + r) * 384 + n] = acc[fm][fn][r] + bias;
    }
  }
}

extern "C" void kernel_launch(void* const* d_in, const int* in_sizes, int n_in,
                              void* d_out, int out_size, void* d_ws, size_t ws_size,
                              hipStream_t stream)
{
  const float* X    = (const float*)d_in[0];
  const float* Wqkv = (const float*)d_in[1];
  const float* posb = (const float*)d_in[2];
  const float* Wo   = (const float*)d_in[3];
  const float* bo   = (const float*)d_in[4];
  const int*   relp = (const int*)d_in[5];
  float* out = (float*)d_out;

  // workspace carve — total 309,657,600 B (proven available)
  char* ws = (char*)d_ws;
  short* WqkvT = (short*)(ws);                 //   884,736 B
  short* WoT   = (short*)(ws + 884736);        //   294,912 B
  float* biasF = (float*)(ws + 1179648);       //   196,608 B
  short* XbfAO = (short*)(ws + 1376256);       // 77,070,336 B : Xbf, then AO
  short* Qb    = (short*)(ws + 78446592);      // 77,070,336 B [win][12][64][32]
  short* Kb    = (short*)(ws + 155516928);     // 77,070,336 B [win][12][64][32]
  short* Vtb   = (short*)(ws + 232587264);     // 77,070,336 B [win][12][32][64]

  prep_kernel<<<2496, 256, 0, stream>>>(Wqkv, Wo, posb, relp, WqkvT, WoT, biasF);
  xcvt_kernel<<<2048, 256, 0, stream>>>(X, XbfAO);
  qkv_gemm<<<7056, 256, 0, stream>>>(XbfAO, WqkvT, Qb, Kb, Vtb);
  // Xbf is dead after qkv_gemm; attn_split reuses the region as AO
  attn_split<<<4704, 256, 0, stream>>>(Qb, Kb, Vtb, biasF, XbfAO);
  proj_kernel<<<2352, 256, 0, stream>>>(XbfAO, WoT, bo, out);
}

// Round 7
// 328.729 us; speedup vs baseline: 1.9807x; 1.0109x over previous
//
#include <hip/hip_runtime.h>

typedef float f32x4 __attribute__((ext_vector_type(4)));
typedef short s16x8 __attribute__((ext_vector_type(8)));

#define MFMA16(A,B,C) __builtin_amdgcn_mfma_f32_16x16x32_bf16((A),(B),(C),0,0,0)

__device__ __forceinline__ short f2bf(float f) {
  union { float f; unsigned u; } v; v.f = f;
  unsigned r = v.u + 0x7FFFu + ((v.u >> 16) & 1u);   // RNE
  return (short)(r >> 16);
}

__device__ __forceinline__ void gload_lds16(const void* g, void* l) {
  __builtin_amdgcn_global_load_lds(
      (const __attribute__((address_space(1))) unsigned*)g,
      (__attribute__((address_space(3))) unsigned*)l, 16, 0, 0);
}

// ---------------- prep: transpose weights to bf16[N][K], gather bias table ----
__global__ __launch_bounds__(256) void prep_kernel(
    const float* __restrict__ Wqkv, const float* __restrict__ Wo,
    const float* __restrict__ posb, const int* __restrict__ relp,
    short* __restrict__ WqkvT, short* __restrict__ WoT, float* __restrict__ biasF)
{
  int i = blockIdx.x * 256 + threadIdx.x;
  if (i < 1152 * 384) {
    int n = i / 384, k = i % 384;
    WqkvT[i] = f2bf(Wqkv[k * 1152 + n]);
  } else if (i < 1152 * 384 + 384 * 384) {
    int j = i - 1152 * 384;
    int n = j / 384, k = j % 384;
    WoT[j] = f2bf(Wo[k * 384 + n]);
  } else {
    int j = i - (1152 * 384 + 384 * 384);    // j < 12*64*64 = 49152
    int h = j >> 12, qk = j & 4095;
    biasF[j] = posb[h * 16129 + relp[qk]];
  }
}

// ---------------- X f32 -> bf16 (memory-bound, vectorized) --------------------
__global__ __launch_bounds__(256) void xcvt_kernel(
    const float* __restrict__ X, short* __restrict__ Xbf)
{
  const int n8 = 4816896;                  // 38,535,168 / 8
  for (int i = blockIdx.x * 256 + threadIdx.x; i < n8; i += gridDim.x * 256) {
    float4 a = *(const float4*)(X + (size_t)i * 8);
    float4 b = *(const float4*)(X + (size_t)i * 8 + 4);
    s16x8 p;
    p[0] = f2bf(a.x); p[1] = f2bf(a.y); p[2] = f2bf(a.z); p[3] = f2bf(a.w);
    p[4] = f2bf(b.x); p[5] = f2bf(b.y); p[6] = f2bf(b.z); p[7] = f2bf(b.w);
    *(s16x8*)(Xbf + (size_t)i * 8) = p;
  }
}

// ---------------- QKV GEMM: Xbf(100352x384) @ WqkvT^T -> Q/K/Vt bf16 ----------
// 128x128 tile, 4 waves 2x2, BK=64, 2-deep counted-vmcnt pipeline (T4) with
// the WAR fix: every wave executes s_waitcnt lgkmcnt(0) BEFORE the second
// s_barrier, so all LDS reads of buf(t&1) are drained chip-wide before any
// wave issues STAGE(t+2) into that buffer (m201-template ordering; R6 raced
// because this drain was missing — rule #18 lets MFMAs+their waits sink past
// the barrier).
__global__ __launch_bounds__(256) void qkv_gemm(
    const short* __restrict__ Xbf, const short* __restrict__ WqkvT,
    short* __restrict__ Qb, short* __restrict__ Kb, short* __restrict__ Vtb)
{
  __shared__ short lds[32768];   // buf sel: A @ sel*16384, B @ sel*16384+8192
  const int bid = blockIdx.x;
  const int wg = (bid & 7) * 882 + (bid >> 3);   // XCD swizzle (7056 = 8*882)
  const int nt = wg % 9, mt = wg / 9;
  const int t = threadIdx.x;
  const int wv = t >> 6, l = t & 63, lr = l & 15, lg = l >> 4;
  const int wm = wv >> 1, wn = wv & 1;

  f32x4 acc[4][4];
#pragma unroll
  for (int fm = 0; fm < 4; ++fm)
#pragma unroll
    for (int fn = 0; fn < 4; ++fn) acc[fm][fn] = (f32x4)0.0f;

  const int srow = wv * 32 + (l >> 3);
  const int cg = (l & 7) ^ (srow & 7);           // srow+8i keeps (row&7) const
  const short* Ab = Xbf   + (size_t)(mt * 128 + srow) * 384 + cg * 8;
  const short* Bb = WqkvT + (size_t)(nt * 128 + srow) * 384 + cg * 8;

#define STAGE(KS, SEL) do {                                                  \
  _Pragma("unroll")                                                          \
  for (int i_ = 0; i_ < 4; ++i_) {                                           \
    gload_lds16(Ab + i_ * 3072 + (KS) * 64,                                  \
                lds + (SEL) * 16384 + (wv * 4 + i_) * 512);                  \
    gload_lds16(Bb + i_ * 3072 + (KS) * 64,                                  \
                lds + (SEL) * 16384 + 8192 + (wv * 4 + i_) * 512);           \
  } } while (0)

#define COMPUTE(SEL) do {                                                    \
  const short* Acur_ = lds + (SEL) * 16384;                                  \
  const short* Bcur_ = Acur_ + 8192;                                         \
  _Pragma("unroll")                                                          \
  for (int kk = 0; kk < 2; ++kk) {                                           \
    s16x8 af[4], bf[4];                                                      \
    _Pragma("unroll")                                                        \
    for (int f = 0; f < 4; ++f) {                                            \
      const int arow = wm * 64 + f * 16 + lr;                                \
      const int ac = (kk * 4 + lg) ^ (arow & 7);                             \
      af[f] = *(const s16x8*)(Acur_ + arow * 64 + ac * 8);                   \
      const int brow = wn * 64 + f * 16 + lr;                                \
      const int bc = (kk * 4 + lg) ^ (brow & 7);                             \
      bf[f] = *(const s16x8*)(Bcur_ + brow * 64 + bc * 8);                   \
    }                                                                        \
    _Pragma("unroll")                                                        \
    for (int fm = 0; fm < 4; ++fm)                                           \
      _Pragma("unroll")                                                      \
      for (int fn = 0; fn < 4; ++fn)                                         \
        acc[fm][fn] = MFMA16(af[fm], bf[fn], acc[fm][fn]);                   \
  } } while (0)

#define ITER(T, WN) do {                                                     \
  asm volatile("s_waitcnt vmcnt(" #WN ")" ::: "memory");                     \
  __builtin_amdgcn_s_barrier();                                              \
  COMPUTE((T) & 1);                                                          \
  asm volatile("s_waitcnt lgkmcnt(0)" ::: "memory");  /* WAR drain */        \
  __builtin_amdgcn_s_barrier();                                              \
  if ((T) + 2 < 6) STAGE((T) + 2, (T) & 1);                                  \
  } while (0)

  STAGE(0, 0);
  STAGE(1, 1);
  ITER(0, 8); ITER(1, 8); ITER(2, 8); ITER(3, 8); ITER(4, 8); ITER(5, 0);
#undef ITER
#undef COMPUTE
#undef STAGE

  // ---- epilogue ----
  const int sel = nt / 3, hq = (nt % 3) * 4;
  if (sel == 2) {
    // V: direct transposed stores Vt[win][h][d][tok] (R3-proven path)
#pragma unroll
    for (int fm = 0; fm < 4; ++fm)
#pragma unroll
      for (int fn = 0; fn < 4; ++fn) {
        const int m0 = wm * 64 + fm * 16 + lg * 4;
        const int win = m0 >> 6, tok0 = m0 & 63;
        const int n = wn * 64 + fn * 16 + lr;
        const int hl = n >> 5, d = n & 31;
        short4 v;
        v.x = f2bf(acc[fm][fn][0]); v.y = f2bf(acc[fm][fn][1]);
        v.z = f2bf(acc[fm][fn][2]); v.w = f2bf(acc[fm][fn][3]);
        *(short4*)(Vtb + (size_t)(mt * 2 + win) * 24576 + (hq + hl) * 2048
                   + d * 64 + tok0) = v;
      }
  } else {
    // Q/K: re-stage tile in LDS (stride 138, bank-coprime), coalesced writes
    __syncthreads();                     // all pipeline reads/writes done
    short* Cl = lds;                     // 128*138 = 17664 shorts, fits
#pragma unroll
    for (int fm = 0; fm < 4; ++fm)
#pragma unroll
      for (int fn = 0; fn < 4; ++fn)
#pragma unroll
        for (int r = 0; r < 4; ++r)
          Cl[(wm * 64 + fm * 16 + lg * 4 + r) * 138 + wn * 64 + fn * 16 + lr] =
              f2bf(acc[fm][fn][r]);
    __syncthreads();
    short* dst0 = (sel ? Kb : Qb) + (size_t)mt * 2 * 24576;
#pragma unroll
    for (int rr = 0; rr < 2; ++rr) {
      const int ro = t * 2 + rr;
      const int win = ro >> 8, hl = (ro >> 6) & 3, tok = ro & 63;
      const int m = win * 64 + tok;
      const short* srcl = Cl + m * 138 + hl * 32;
      int4 a0 = *(const int4*)(srcl);
      int4 a1 = *(const int4*)(srcl + 8);
      int4 a2 = *(const int4*)(srcl + 16);
      int4 a3 = *(const int4*)(srcl + 24);
      short* dp = dst0 + win * 24576 + (hq + hl) * 2048 + tok * 32;
      *(int4*)(dp)      = a0;
      *(int4*)(dp + 8)  = a1;
      *(int4*)(dp + 16) = a2;
      *(int4*)(dp + 24) = a3;
    }
  }
}

// ---------------- attention: one wave per (window, head) ----------------------
__global__ __launch_bounds__(256) void attn_split(
    const short* __restrict__ Qb, const short* __restrict__ Kb,
    const short* __restrict__ Vtb, const float* __restrict__ biasF,
    short* __restrict__ AO)
{
  __shared__ short obuf[10240];          // 4 waves * [64][40]
  const int bid = blockIdx.x;
  const int wg = (bid & 7) * 588 + (bid >> 3);   // XCD swizzle (4704 = 8*588)
  const int wv = threadIdx.x >> 6;
  const int l = threadIdx.x & 63, lr = l & 15, lg = l >> 4;
  const int p = wg * 4 + wv;                     // (w,h) pair, p = w*12 + h
  const int w = p / 12, h = p % 12;

  const short* Kp = Kb + (size_t)p * 2048;
  const short* Qp = Qb + (size_t)p * 2048;
  const short* Vp = Vtb + (size_t)p * 2048;
  const float* bh = biasF + h * 4096;

  s16x8 ka[4], qf[4];
#pragma unroll
  for (int f = 0; f < 4; ++f) {
    ka[f] = *(const s16x8*)(Kp + (f * 16 + lr) * 32 + lg * 8);
    qf[f] = *(const s16x8*)(Qp + (f * 16 + lr) * 32 + lg * 8);
  }
  s16x8 va[2][2];
#pragma unroll
  for (int fd = 0; fd < 2; ++fd)
#pragma unroll
    for (int kb = 0; kb < 2; ++kb) {
      short4 v0 = *(const short4*)(Vp + (fd * 16 + lr) * 64 + kb * 32 + lg * 4);
      short4 v1 = *(const short4*)(Vp + (fd * 16 + lr) * 64 + kb * 32 + 16 + lg * 4);
      s16x8 tv;
      tv[0] = v0.x; tv[1] = v0.y; tv[2] = v0.z; tv[3] = v0.w;
      tv[4] = v1.x; tv[5] = v1.y; tv[6] = v1.z; tv[7] = v1.w;
      va[fd][kb] = tv;
    }

  // S^T = K·Q^T  (rows kt, cols q), K-dim 32
  f32x4 st[4][4];
#pragma unroll
  for (int fk = 0; fk < 4; ++fk)
#pragma unroll
    for (int fq = 0; fq < 4; ++fq)
      st[fk][fq] = MFMA16(ka[fk], qf[fq], (f32x4)0.0f);

  // scale + bias + softmax over kt (per q column, per-lane + shfl 16/32)
#pragma unroll
  for (int fq = 0; fq < 4; ++fq) {
    const int q = fq * 16 + lr;
    float4 bv[4];
#pragma unroll
    for (int fk = 0; fk < 4; ++fk)
      bv[fk] = *(const float4*)(bh + q * 64 + fk * 16 + lg * 4);
    float mx = -3.0e38f;
#pragma unroll
    for (int fk = 0; fk < 4; ++fk)
#pragma unroll
      for (int r = 0; r < 4; ++r) {
        float v = st[fk][fq][r] * 0.17677669529663687f + ((const float*)&bv[fk])[r];
        st[fk][fq][r] = v;
        mx = fmaxf(mx, v);
      }
    mx = fmaxf(mx, __shfl_xor(mx, 16));
    mx = fmaxf(mx, __shfl_xor(mx, 32));
    float sm = 0.0f;
#pragma unroll
    for (int fk = 0; fk < 4; ++fk)
#pragma unroll
      for (int r = 0; r < 4; ++r) {
        float e = __expf(st[fk][fq][r] - mx);
        st[fk][fq][r] = e;
        sm += e;
      }
    sm += __shfl_xor(sm, 16);
    sm += __shfl_xor(sm, 32);
    const float inv = 1.0f / sm;
#pragma unroll
    for (int fk = 0; fk < 4; ++fk)
#pragma unroll
      for (int r = 0; r < 4; ++r) st[fk][fq][r] *= inv;
  }

  // O^T = V^T · P^T ; sigma(g,j)=32kb+16(j>>2)+4g+(j&3) on both operands
  f32x4 ot[2][4];
#pragma unroll
  for (int fd = 0; fd < 2; ++fd)
#pragma unroll
    for (int fq = 0; fq < 4; ++fq) ot[fd][fq] = (f32x4)0.0f;
#pragma unroll
  for (int kb = 0; kb < 2; ++kb)
#pragma unroll
    for (int fq = 0; fq < 4; ++fq) {
      s16x8 pb;
#pragma unroll
      for (int j = 0; j < 8; ++j)
        pb[j] = f2bf(st[2 * kb + (j >> 2)][fq][j & 3]);   // lane-local repack
#pragma unroll
      for (int fd = 0; fd < 2; ++fd)
        ot[fd][fq] = MFMA16(va[fd][kb], pb, ot[fd][fq]);
    }

  // epilogue: stage [q][d] per-wave in LDS, write coalesced 16B rows
  short* ob = obuf + wv * 2560;
#pragma unroll
  for (int fd = 0; fd < 2; ++fd)
#pragma unroll
    for (int fq = 0; fq < 4; ++fq)
#pragma unroll
      for (int r = 0; r < 4; ++r)
        ob[(fq * 16 + lr) * 40 + fd * 16 + lg * 4 + r] = f2bf(ot[fd][fq][r]);
  short* dst = AO + ((size_t)w * 64 + l) * 384 + h * 32;
  int4 o0 = *(const int4*)(ob + l * 40);
  int4 o1 = *(const int4*)(ob + l * 40 + 8);
  int4 o2 = *(const int4*)(ob + l * 40 + 16);
  int4 o3 = *(const int4*)(ob + l * 40 + 24);
  *(int4*)(dst)      = o0;
  *(int4*)(dst + 8)  = o1;
  *(int4*)(dst + 16) = o2;
  *(int4*)(dst + 24) = o3;
}

// ---------------- output projection: out = AO(bf16) @ Wo + bo, f32 out --------
// Same 2-deep counted-vmcnt pipeline as qkv_gemm (with the lgkm WAR drain).
__global__ __launch_bounds__(256) void proj_kernel(
    const short* __restrict__ AO, const short* __restrict__ WoT,
    const float* __restrict__ bo, float* __restrict__ out)
{
  __shared__ short lds[32768];
  const int bid = blockIdx.x;
  const int wg = (bid & 7) * 294 + (bid >> 3);   // XCD swizzle (2352 = 8*294)
  const int nt = wg % 3, mt = wg / 3;
  const int t = threadIdx.x;
  const int wv = t >> 6, l = t & 63, lr = l & 15, lg = l >> 4;
  const int wm = wv >> 1, wn = wv & 1;

  f32x4 acc[4][4];
#pragma unroll
  for (int fm = 0; fm < 4; ++fm)
#pragma unroll
    for (int fn = 0; fn < 4; ++fn) acc[fm][fn] = (f32x4)0.0f;

  const int srow = wv * 32 + (l >> 3);
  const int cg = (l & 7) ^ (srow & 7);
  const short* Ab = AO  + (size_t)(mt * 128 + srow) * 384 + cg * 8;
  const short* Bb = WoT + (size_t)(nt * 128 + srow) * 384 + cg * 8;

#define STAGE(KS, SEL) do {                                                  \
  _Pragma("unroll")                                                          \
  for (int i_ = 0; i_ < 4; ++i_) {                                           \
    gload_lds16(Ab + i_ * 3072 + (KS) * 64,                                  \
                lds + (SEL) * 16384 + (wv * 4 + i_) * 512);                  \
    gload_lds16(Bb + i_ * 3072 + (KS) * 64,                                  \
                lds + (SEL) * 16384 + 8192 + (wv * 4 + i_) * 512);           \
  } } while (0)

#define COMPUTE(SEL) do {                                                    \
  const short* Acur_ = lds + (SEL) * 16384;                                  \
  const short* Bcur_ = Acur_ + 8192;                                         \
  _Pragma("unroll")                                                          \
  for (int kk = 0; kk < 2; ++kk) {                                           \
    s16x8 af[4], bf[4];                                                      \
    _Pragma("unroll")                                                        \
    for (int f = 0; f < 4; ++f) {                                            \
      const int arow = wm * 64 + f * 16 + lr;                                \
      const int ac = (kk * 4 + lg) ^ (arow & 7);                             \
      af[f] = *(const s16x8*)(Acur_ + arow * 64 + ac * 8);                   \
      const int brow = wn * 64 + f * 16 + lr;                                \
      const int bc = (kk * 4 + lg) ^ (brow & 7);                             \
      bf[f] = *(const s16x8*)(Bcur_ + brow * 64 + bc * 8);                   \
    }                                                                        \
    _Pragma("unroll")                                                        \
    for (int fm = 0; fm < 4; ++fm)                                           \
      _Pragma("unroll")                                                      \
      for (int fn = 0; fn < 4; ++fn)                                         \
        acc[fm][fn] = MFMA16(af[fm], bf[fn], acc[fm][fn]);                   \
  } } while (0)

#define ITER(T, WN) do {                                                     \
  asm volatile("s_waitcnt vmcnt(" #WN ")" ::: "memory");                     \
  __builtin_amdgcn_s_barrier();                                              \
  COMPUTE((T) & 1);                                                          \
  asm volatile("s_waitcnt lgkmcnt(0)" ::: "memory");  /* WAR drain */        \
  __builtin_amdgcn_s_barrier();                                              \
  if ((T) + 2 < 6) STAGE((T) + 2, (T) & 1);                                  \
  } while (0)

  STAGE(0, 0);
  STAGE(1, 1);
  ITER(0, 8); ITER(1, 8); ITER(2, 8); ITER(3, 8); ITER(4, 8); ITER(5, 0);
#undef ITER
#undef COMPUTE
#undef STAGE

#pragma unroll
  for (int fn = 0; fn < 4; ++fn) {
    const int n = nt * 128 + wn * 64 + fn * 16 + lr;
    const float bias = bo[n];
#pragma unroll
    for (int fm = 0; fm < 4; ++fm) {
      const int m0 = mt * 128 + wm * 64 + fm * 16 + lg * 4;
#pragma unroll
      for (int r = 0; r < 4; ++r)
        out[(size_t)(m0 + r) * 384 + n] = acc[fm][fn][r] + bias;
    }
  }
}

extern "C" void kernel_launch(void* const* d_in, const int* in_sizes, int n_in,
                              void* d_out, int out_size, void* d_ws, size_t ws_size,
                              hipStream_t stream)
{
  const float* X    = (const float*)d_in[0];
  const float* Wqkv = (const float*)d_in[1];
  const float* posb = (const float*)d_in[2];
  const float* Wo   = (const float*)d_in[3];
  const float* bo   = (const float*)d_in[4];
  const int*   relp = (const int*)d_in[5];
  float* out = (float*)d_out;

  // workspace carve — total 309,657,600 B (proven available)
  char* ws = (char*)d_ws;
  short* WqkvT = (short*)(ws);                 //   884,736 B
  short* WoT   = (short*)(ws + 884736);        //   294,912 B
  float* biasF = (float*)(ws + 1179648);       //   196,608 B
  short* XbfAO = (short*)(ws + 1376256);       // 77,070,336 B : Xbf, then AO
  short* Qb    = (short*)(ws + 78446592);      // 77,070,336 B [win][12][64][32]
  short* Kb    = (short*)(ws + 155516928);     // 77,070,336 B [win][12][64][32]
  short* Vtb   = (short*)(ws + 232587264);     // 77,070,336 B [win][12][32][64]

  prep_kernel<<<2496, 256, 0, stream>>>(Wqkv, Wo, posb, relp, WqkvT, WoT, biasF);
  xcvt_kernel<<<2048, 256, 0, stream>>>(X, XbfAO);
  qkv_gemm<<<7056, 256, 0, stream>>>(XbfAO, WqkvT, Qb, Kb, Vtb);
  // Xbf is dead after qkv_gemm; attn_split reuses the region as AO
  attn_split<<<4704, 256, 0, stream>>>(Qb, Kb, Vtb, biasF, XbfAO);
  proj_kernel<<<2352, 256, 0, stream>>>(XbfAO, WoT, bo, out);
}